// Round 7
// baseline (978.394 us; speedup 1.0000x reference)
//
#include <hip/hip_runtime.h>
#include <cfloat>
#include <cstdint>

// Problem constants (fixed by the reference: N=65536, D=256, K=4096)
constexpr int N  = 65536;
constexpr int D  = 256;
constexpr int K  = 4096;

typedef __attribute__((ext_vector_type(8))) _Float16 half8;          // fp16x8 MFMA frag
typedef __attribute__((ext_vector_type(8))) unsigned short ushort8;  // 16B vector
typedef __attribute__((ext_vector_type(4))) float floatx4;

__device__ __forceinline__ floatx4 mfma_f16(half8 a, half8 b, floatx4 c) {
    return __builtin_amdgcn_mfma_f32_16x16x32_f16(a, b, c, 0, 0, 0);
}

// async global->LDS, 16B per lane; LDS dest = uniform base + lane*16 (m97 semantics)
__device__ __forceinline__ void ld_lds16(void* lds, const void* g) {
    __builtin_amdgcn_global_load_lds(
        (const __attribute__((address_space(1))) unsigned int*)g,
        (__attribute__((address_space(3))) unsigned int*)lds, 16, 0, 0);
}

// ---------------- c2[k] = sum_d C[k][d]^2 (exact fp32) ----------------
__global__ void prep_c2(const float* __restrict__ C, float* __restrict__ c2) {
    int k = blockIdx.x;
    int l = threadIdx.x;                 // 64 threads = 1 wave per center row
    const float4* row = (const float4*)(C + (size_t)k * D);
    float4 v = row[l];
    float s = v.x*v.x + v.y*v.y + v.z*v.z + v.w*v.w;
    #pragma unroll
    for (int m = 1; m < 64; m <<= 1) s += __shfl_xor(s, m);
    if (l == 0) c2[k] = s;
}

// ------- fp32 -> fp16 (RTN), X and C in one launch; also accumulates sum(x^2) -------
__global__ void convert_f16_both(const float* __restrict__ X, const float* __restrict__ C,
                                 unsigned short* __restrict__ Xh,
                                 unsigned short* __restrict__ Ch,
                                 double* __restrict__ lossAcc) {
    int id = blockIdx.x * 256 + threadIdx.x;
    const int nX = N * D / 8;
    bool isX = id < nX;
    const float* src; unsigned short* dst;
    if (isX) { src = X; dst = Xh; }
    else     { src = C; dst = Ch; id -= nX; }
    const float4* s4 = (const float4*)src;
    float4 a = s4[2*id], b = s4[2*id+1];
    float xs[8] = {a.x,a.y,a.z,a.w,b.x,b.y,b.z,b.w};
    ushort8 h;
    float ps = 0.f;
    #pragma unroll
    for (int i = 0; i < 8; ++i) {
        union { _Float16 f; unsigned short u; } cv;
        cv.f = (_Float16)xs[i];
        h[i] = cv.u;
        ps += xs[i]*xs[i];
    }
    ((ushort8*)dst)[id] = h;
    if (isX) {   // block 0..8191 are pure-X: wave-uniform branch
        #pragma unroll
        for (int m = 1; m < 64; m <<= 1) ps += __shfl_xor(ps, m);
        if ((threadIdx.x & 63) == 0) atomicAdd(lossAcc, (double)ps);
    }
}

// ---------------- fp16 MFMA GEMM + fused top-2 argmin ----------------
// Grid (N/128, 4): blockIdx.y = kb picks a 1024-center K-slice.
// A (128x256) staged ONCE via global_load_lds(16B); B double-buffered per
// 32-depth chunk, also global_load_lds. One barrier per chunk. LDS layout is
// lane-ordered (no pad); bank conflicts avoided by XOR depth-group swizzle
// applied on the GLOBAL address side: slot s holds group s ^ ((row>>1)&3).
// 256 thr = 4 waves (2x2), wave tile 64x64 = 4x4 frags 16x16x32 fp16.
// Score = c2[col] - 2*dot (x2 omitted: row-constant, argmin-invariant).
// Output: cand[row][h], h = 2*kb + wn in [0,8): (v1,idx1,v2,idx2) per 512-col group.
__global__ __launch_bounds__(256, 2) void mfma_assign(
        const unsigned short* __restrict__ Xh, const unsigned short* __restrict__ Ch,
        const float* __restrict__ c2, float* __restrict__ cand)
{
    __shared__ __align__(16) unsigned short sA[8*128*4*8];   // 64 KB: (dk,row,slot)x8h
    __shared__ __align__(16) unsigned short sB[2*128*4*8];   // 16 KB: (buf,row,slot)x8h

    const int t    = threadIdx.x;
    const int w    = t >> 6, l = t & 63;
    const int quad = l >> 4, lr = l & 15;
    const int wm   = w >> 1, wn = w & 1;
    const int rowbase = blockIdx.x * 128;
    const int kb   = blockIdx.y;                 // 0..3

    const int rl  = l >> 2;                      // staging local row (0..15)
    const int gsw = (l & 3) ^ ((l >> 3) & 3);    // swizzled depth-group to fetch

    // ---- stage B chunk 0 (ct = kb*8, dk = 0) into buf 0 ----
    #pragma unroll
    for (int k = 0; k < 2; ++k) {
        int q = 2*w + k;                                       // 0..7
        const unsigned short* gp = Ch + (size_t)(kb*1024 + q*16 + rl)*D + gsw*8;
        ld_lds16((char*)sB + q*1024, gp);
    }
    // ---- stage A: all 8 depth-chunks (64 calls, 16 per wave) ----
    #pragma unroll
    for (int k = 0; k < 16; ++k) {
        int q = w*16 + k;                                      // 0..63
        int c = q >> 3, rb = (q & 7) * 16;
        const unsigned short* gp = Xh + (size_t)(rowbase + rb + rl)*D + c*32 + gsw*8;
        ld_lds16((char*)sA + q*1024, gp);
    }

    // frag-read byte offsets (swizzle: slot = quad ^ ((lr>>1)&3); 2-way banks = free)
    const int sA_off = ((64*wm + lr)*4 + (quad ^ ((lr>>1)&3)))*16;
    const int sB_off = ((64*wn + lr)*4 + (quad ^ ((lr>>1)&3)))*16;

    // per-lane running top-2 per owned row (16 rows: st = 4*i + r)
    float v1[16], v2[16]; int x1[16], x2s[16];
    #pragma unroll
    for (int i = 0; i < 16; ++i) { v1[i]=FLT_MAX; v2[i]=FLT_MAX; x1[i]=0x7fffffff; x2s[i]=0x7fffffff; }

    floatx4 acc[4][4];
    float c2v[4]; int jidx[4];
    int buf = 0;

    for (int chunk = 0; chunk < 64; ++chunk) {
        const int dk = chunk & 7;
        const int ct = kb*8 + (chunk >> 3);

        if (dk == 0) {
            #pragma unroll
            for (int i = 0; i < 4; ++i)
                #pragma unroll
                for (int j = 0; j < 4; ++j) acc[i][j] = (floatx4)0.f;
            const int colbase = ct*128 + 64*wn;
            #pragma unroll
            for (int j = 0; j < 4; ++j) {
                int col = colbase + 16*j + lr;
                c2v[j] = c2[col]; jidx[j] = col;
            }
        }

        __syncthreads();   // drains this wave's global_load_lds (incl. this chunk's B)

        if (chunk < 63) {  // prefetch next B chunk into the other buffer
            int nc = chunk + 1;
            int nct = kb*8 + (nc >> 3), ndk = nc & 7;
            #pragma unroll
            for (int k = 0; k < 2; ++k) {
                int q = 2*w + k;
                const unsigned short* gp = Ch + (size_t)(nct*128 + q*16 + rl)*D + ndk*32 + gsw*8;
                ld_lds16((char*)sB + (buf^1)*8192 + q*1024, gp);
            }
        }

        half8 Af[4], Bf[4];
        #pragma unroll
        for (int i = 0; i < 4; ++i)
            Af[i] = *(const half8*)((const char*)sA + dk*8192 + i*1024 + sA_off);
        #pragma unroll
        for (int j = 0; j < 4; ++j)
            Bf[j] = *(const half8*)((const char*)sB + buf*8192 + j*1024 + sB_off);
        #pragma unroll
        for (int j = 0; j < 4; ++j)
            #pragma unroll
            for (int i = 0; i < 4; ++i)
                acc[i][j] = mfma_f16(Af[i], Bf[j], acc[i][j]);

        if (dk == 7) {
            // fused top-2 merge: rows st=4i+r (row=64wm+16i+4quad+r), cols jidx[j]
            #pragma unroll
            for (int i = 0; i < 4; ++i)
                #pragma unroll
                for (int j = 0; j < 4; ++j)
                    #pragma unroll
                    for (int r = 0; r < 4; ++r) {
                        float s = fmaf(-2.f, acc[i][j][r], c2v[j]);
                        int st = 4*i + r;
                        bool cA = s < v1[st];
                        bool cB = s < v2[st];
                        float tv = cB ? s : v2[st]; int tx = cB ? jidx[j] : x2s[st];
                        v2[st] = cA ? v1[st] : tv;  x2s[st] = cA ? x1[st] : tx;
                        v1[st] = cA ? s : v1[st];   x1[st]  = cA ? jidx[j] : x1[st];
                    }
        }
        buf ^= 1;
    }

    // final cross-lane (16 lr lanes) top-2 butterfly per owned row, then write
    #pragma unroll
    for (int i = 0; i < 4; ++i)
        #pragma unroll
        for (int r = 0; r < 4; ++r) {
            int st = 4*i + r;
            float a1 = v1[st], a2 = v2[st]; int ax1 = x1[st], ax2 = x2s[st];
            #pragma unroll
            for (int m = 1; m < 16; m <<= 1) {
                float b1f = __shfl_xor(a1, m); int bx1 = __shfl_xor(ax1, m);
                float b2f = __shfl_xor(a2, m); int bx2 = __shfl_xor(ax2, m);
                bool tt = (b1f < a1) || (b1f == a1 && bx1 < ax1);
                float n1 = tt ? b1f : a1; int nx1 = tt ? bx1 : ax1;
                float w1 = tt ? a1 : b1f; int wx1 = tt ? ax1 : bx1;  // loser of firsts
                float w2 = tt ? b2f : a2; int wx2 = tt ? bx2 : ax2;  // winner's second
                bool uu = (w2 < w1) || (w2 == w1 && wx2 < wx1);
                a1 = n1; ax1 = nx1;
                a2 = uu ? w2 : w1; ax2 = uu ? wx2 : wx1;
            }
            if (lr == 0) {
                int row = rowbase + 64*wm + 16*i + 4*quad + r;
                float4 o; o.x = a1; o.y = __int_as_float(ax1);
                o.z = a2; o.w = __int_as_float(ax2);
                ((float4*)cand)[(size_t)row*8 + 2*kb + wn] = o;
            }
        }
}

// ------- margin-gated exact recheck + labels + histogram (no loss here) ------
// One wave per point. 16 candidates (top-2 x 8 groups). If global approx
// top-2 margin > 0.25 (>>10 sigma of fp16 score error), label is certain
// and NOTHING else is read; else exact fp32 d2 (numpy rounding order) over
// candidates within 0.25 of the approx min (ballot-filtered, typically 2).
__global__ __launch_bounds__(256) void recheck_label(
        const float* __restrict__ X, const float* __restrict__ C,
        const float* __restrict__ c2, const float* __restrict__ cand,
        float* __restrict__ out_labels, int* __restrict__ labInt,
        int* __restrict__ cnt)
{
    int t = threadIdx.x, w = t >> 6, l = t & 63;
    int row = blockIdx.x * 4 + w;

    float s = FLT_MAX; int idx = 0x7fffffff;
    if (l < 16) {
        float4 e = ((const float4*)cand)[(size_t)row*8 + (l >> 1)];
        s   = (l & 1) ? e.z : e.x;
        idx = (l & 1) ? __float_as_int(e.w) : __float_as_int(e.y);
    }

    // global top-2 butterfly over the 16 candidate lanes (tie-break: smaller idx)
    float a1 = s, a2 = FLT_MAX; int ax1 = idx, ax2 = 0x7fffffff;
    #pragma unroll
    for (int m = 1; m < 16; m <<= 1) {
        float b1 = __shfl_xor(a1, m); int bx1 = __shfl_xor(ax1, m);
        float b2 = __shfl_xor(a2, m); int bx2 = __shfl_xor(ax2, m);
        bool tt = (b1 < a1) || (b1 == a1 && bx1 < ax1);
        float n1 = tt ? b1 : a1; int nx1 = tt ? bx1 : ax1;
        float w1 = tt ? a1 : b1; int wx1 = tt ? ax1 : bx1;
        float w2 = tt ? b2 : a2; int wx2 = tt ? bx2 : ax2;
        bool uu = (w2 < w1) || (w2 == w1 && wx2 < wx1);
        a1 = n1; ax1 = nx1;
        a2 = uu ? w2 : w1; ax2 = uu ? wx2 : wx1;
    }
    float s1 = __shfl(a1, 0), s2 = __shfl(a2, 0);
    int   i1 = __shfl(ax1, 0);

    int label;
    if (s2 - s1 > 0.25f) {          // wave-uniform fast path: no memory traffic
        label = i1;
    } else {
        float4 xv = ((const float4*)X)[(size_t)row*64 + l];
        float px = xv.x*xv.x + xv.y*xv.y + xv.z*xv.z + xv.w*xv.w;
        #pragma unroll
        for (int m = 1; m < 64; m <<= 1) px += __shfl_xor(px, m);
        bool active = (l < 16) && (s <= s1 + 0.25f);
        unsigned long long mask = __ballot(active);
        float best = FLT_MAX; int bi = 0x7fffffff;
        while (mask) {
            int k = __ffsll((long long)mask) - 1;
            mask &= mask - 1;
            int ck = __shfl(idx, k);
            float4 cv = ((const float4*)C)[(size_t)ck*64 + l];
            float pd = xv.x*cv.x + xv.y*cv.y + xv.z*cv.z + xv.w*cv.w;
            #pragma unroll
            for (int m = 1; m < 64; m <<= 1) pd += __shfl_xor(pd, m);
            float d2 = fmaf(-2.f, pd, px) + c2[ck];   // numpy's rounding order
            if (d2 < best || (d2 == best && ck < bi)) { best = d2; bi = ck; }
        }
        label = bi;
    }

    if (l == 0) {
        out_labels[row] = (float)label;
        labInt[row] = label;
        atomicAdd(&cnt[label], 1);
    }
}

// ---------------- exclusive prefix sum of the 4096-bin histogram -------------
__global__ void prefix_kernel(const int* __restrict__ cnt,
                              int* __restrict__ offs, int* __restrict__ cursor) {
    int l = threadIdx.x;                 // 64 lanes, 64 bins each
    int s = 0;
    #pragma unroll 8
    for (int i = 0; i < 64; ++i) s += cnt[l*64 + i];
    int inc = s;
    #pragma unroll
    for (int off = 1; off < 64; off <<= 1) {
        int u = __shfl_up(inc, off);
        if (l >= off) inc += u;
    }
    int run = inc - s;                   // exclusive lane base
    for (int i = 0; i < 64; ++i) {
        int k = l*64 + i;
        offs[k] = run; cursor[k] = run;
        run += cnt[k];
    }
}

// ---------------- bucket rows by label (one position atomic per row) ---------
__global__ void scatter_idx(const int* __restrict__ labInt,
                            int* __restrict__ cursor, int* __restrict__ sortedIdx) {
    int i = blockIdx.x * 256 + threadIdx.x;
    int lab = labInt[i];
    int pos = atomicAdd(&cursor[lab], 1);
    sortedIdx[pos] = i;
}

// -- atomic-free segment sum (block per center) + finalize + loss center-terms --
// loss = sum(x^2) [from convert] + sum_k (m_k*|c_k|^2 - 2*c_k.seg_k) [here]
__global__ __launch_bounds__(256) void center_update(
        const float* __restrict__ X, const float* __restrict__ C,
        const int* __restrict__ counts0, const int* __restrict__ cnt,
        const int* __restrict__ offs, const int* __restrict__ sortedIdx,
        double* __restrict__ lossAcc, float* __restrict__ out)
{
    __shared__ float red[4];
    int k = blockIdx.x, d = threadIdx.x;   // d = dim (D == 256 == blockDim)
    int start = offs[k], m = cnt[k];
    float acc = 0.f;
    int i = 0;
    for (; i + 4 <= m; i += 4) {
        int r0 = sortedIdx[start+i],   r1 = sortedIdx[start+i+1];
        int r2 = sortedIdx[start+i+2], r3 = sortedIdx[start+i+3];
        float a0 = X[(size_t)r0*D + d], a1 = X[(size_t)r1*D + d];
        float a2 = X[(size_t)r2*D + d], a3 = X[(size_t)r3*D + d];
        acc += (a0 + a1) + (a2 + a3);
    }
    for (; i < m; ++i) acc += X[(size_t)sortedIdx[start+i]*D + d];

    float cv = C[(size_t)k*D + d];
    float c0 = (float)counts0[k];
    out[N + (size_t)k*D + d] = (c0 * cv + acc) / (c0 + (float)m);
    if (d == 0) out[N + (size_t)K*D + k] = (float)(counts0[k] + m);

    // loss center-term: cv*(m*cv - 2*acc), reduced over d then one double atomic
    float lp = cv * fmaf((float)m, cv, -2.f*acc);
    #pragma unroll
    for (int s = 1; s < 64; s <<= 1) lp += __shfl_xor(lp, s);
    if ((d & 63) == 0) red[d >> 6] = lp;
    __syncthreads();
    if (d == 0) atomicAdd(lossAcc, (double)(red[0] + red[1] + red[2] + red[3]));
}

// ---------------- final loss write ----------------
__global__ void loss_final(const double* __restrict__ lossAcc, float* __restrict__ out) {
    out[N + (size_t)K*D + K] = (float)(lossAcc[0] / (double)N);
}

// ---------------- finalize (fallback path only) ----------------
__global__ void finalize_kernel(const float* __restrict__ C,
                                const int* __restrict__ counts0,
                                const float* __restrict__ seg,
                                const int* __restrict__ cnt,
                                const double* __restrict__ lossAcc,
                                float* __restrict__ out)
{
    int g = blockIdx.x * 256 + threadIdx.x;   // 0 .. K*D-1
    int k = g >> 8;                           // D = 256
    float c0 = (float)counts0[k];
    float m  = (float)cnt[k];
    out[N + g] = (c0 * C[g] + seg[g]) / (c0 + m);
    if (g < K) out[N + (size_t)K*D + g] = (float)(counts0[g] + cnt[g]);
    if (g == 0) out[N + (size_t)K*D + K] = (float)(lossAcc[0] / (double)N);
}

// ================= fallback (round-1 proven fp32 path, small ws) =============
__global__ __launch_bounds__(256, 2) void assign_fp32(
        const float* __restrict__ X, const float* __restrict__ C,
        const float* __restrict__ c2, float* __restrict__ out_labels,
        float* __restrict__ seg, int* __restrict__ cnt,
        double* __restrict__ lossAcc)
{
    constexpr int BM = 128, BN = 128, KD = 16;
    __shared__ float As[KD][BM];
    __shared__ float Bs[KD][BN];
    __shared__ float x2f[BM];
    __shared__ int   labs[BM];

    const int t  = threadIdx.x;
    const int tx = t & 15;
    const int ty = t >> 4;
    const int rowbase = blockIdx.x * BM;

    {
        int r  = t >> 1;
        int dh = (t & 1) * (D / 2);
        const float4* xr = (const float4*)(X + (size_t)(rowbase + r) * D + dh);
        float s = 0.f;
        #pragma unroll
        for (int i = 0; i < D / 8; ++i) {
            float4 v = xr[i];
            s += v.x*v.x + v.y*v.y + v.z*v.z + v.w*v.w;
        }
        s += __shfl_xor(s, 1);
        if ((t & 1) == 0) x2f[r] = s;
    }
    __syncthreads();

    float x2v[8];
    #pragma unroll
    for (int i = 0; i < 4; ++i) { x2v[i] = x2f[4*ty + i]; x2v[i+4] = x2f[64 + 4*ty + i]; }

    float rmv[8]; int rmi[8];
    #pragma unroll
    for (int i = 0; i < 8; ++i) { rmv[i] = FLT_MAX; rmi[i] = 0x7fffffff; }

    for (int ct = 0; ct < K / BN; ++ct) {
        float acc[8][8];
        #pragma unroll
        for (int i = 0; i < 8; ++i)
            #pragma unroll
            for (int j = 0; j < 8; ++j) acc[i][j] = 0.f;

        float c2f2[8];
        {
            float4 a = *(const float4*)(c2 + ct*BN + 4*tx);
            float4 b = *(const float4*)(c2 + ct*BN + 64 + 4*tx);
            c2f2[0]=a.x; c2f2[1]=a.y; c2f2[2]=a.z; c2f2[3]=a.w;
            c2f2[4]=b.x; c2f2[5]=b.y; c2f2[6]=b.z; c2f2[7]=b.w;
        }

        for (int dk = 0; dk < D / KD; ++dk) {
            #pragma unroll
            for (int i = 0; i < 2; ++i) {
                int f  = t + 256 * i;
                int r  = f >> 2;
                int dp = f & 3;
                float4 av = *(const float4*)(X + (size_t)(rowbase + r) * D + dk*KD + 4*dp);
                float4 bv = *(const float4*)(C + (size_t)(ct*BN + r) * D + dk*KD + 4*dp);
                As[4*dp+0][r]=av.x; As[4*dp+1][r]=av.y; As[4*dp+2][r]=av.z; As[4*dp+3][r]=av.w;
                Bs[4*dp+0][r]=bv.x; Bs[4*dp+1][r]=bv.y; Bs[4*dp+2][r]=bv.z; Bs[4*dp+3][r]=bv.w;
            }
            __syncthreads();
            #pragma unroll
            for (int kk = 0; kk < KD; ++kk) {
                float4 a0 = *(const float4*)&As[kk][4*ty];
                float4 a1 = *(const float4*)&As[kk][64 + 4*ty];
                float4 b0 = *(const float4*)&Bs[kk][4*tx];
                float4 b1 = *(const float4*)&Bs[kk][64 + 4*tx];
                float av[8] = {a0.x,a0.y,a0.z,a0.w,a1.x,a1.y,a1.z,a1.w};
                float bv[8] = {b0.x,b0.y,b0.z,b0.w,b1.x,b1.y,b1.z,b1.w};
                #pragma unroll
                for (int i = 0; i < 8; ++i)
                    #pragma unroll
                    for (int j = 0; j < 8; ++j)
                        acc[i][j] = fmaf(av[i], bv[j], acc[i][j]);
            }
            __syncthreads();
        }

        #pragma unroll
        for (int i = 0; i < 8; ++i) {
            float bv = FLT_MAX; int bi = 0x7fffffff;
            #pragma unroll
            for (int j = 0; j < 8; ++j) {
                int coll = (j < 4) ? (4*tx + j) : (64 + 4*tx + (j - 4));
                float v = fmaf(-2.f, acc[i][j], x2v[i]) + c2f2[j];
                int idx = ct * BN + coll;
                if (v < bv || (v == bv && idx < bi)) { bv = v; bi = idx; }
            }
            #pragma unroll
            for (int m = 1; m < 16; m <<= 1) {
                float ov = __shfl_xor(bv, m);
                int   oi = __shfl_xor(bi, m);
                if (ov < bv || (ov == bv && oi < bi)) { bv = ov; bi = oi; }
            }
            if (bv < rmv[i] || (bv == rmv[i] && bi < rmi[i])) { rmv[i] = bv; rmi[i] = bi; }
        }
    }

    if (tx == 0) {
        #pragma unroll
        for (int i = 0; i < 8; ++i) {
            int r = (i < 4) ? (4*ty + i) : (64 + 4*ty + (i - 4));
            labs[r] = rmi[i];
            out_labels[rowbase + r] = (float)rmi[i];
            atomicAdd(&cnt[rmi[i]], 1);
        }
    }
    __syncthreads();

    {
        int r   = t >> 1;
        int dh  = (t & 1) * (D / 2);
        int lab = labs[r];
        const float4* xr = (const float4*)(X + (size_t)(rowbase + r) * D + dh);
        const float4* cr = (const float4*)(C + (size_t)lab * D + dh);
        float* sp = seg + (size_t)lab * D + dh;
        float ls = 0.f;
        #pragma unroll 8
        for (int i = 0; i < D / 8; ++i) {
            float4 xv = xr[i];
            float4 cv = cr[i];
            atomicAdd(sp + 4*i + 0, xv.x);
            atomicAdd(sp + 4*i + 1, xv.y);
            atomicAdd(sp + 4*i + 2, xv.z);
            atomicAdd(sp + 4*i + 3, xv.w);
            float d0 = xv.x - cv.x, d1 = xv.y - cv.y;
            float d2 = xv.z - cv.z, d3 = xv.w - cv.w;
            ls += d0*d0 + d1*d1 + d2*d2 + d3*d3;
        }
        #pragma unroll
        for (int m = 1; m < 64; m <<= 1) ls += __shfl_xor(ls, m);
        if ((t & 63) == 0) atomicAdd(lossAcc, (double)ls);
    }
}

extern "C" void kernel_launch(void* const* d_in, const int* in_sizes, int n_in,
                              void* d_out, int out_size, void* d_ws, size_t ws_size,
                              hipStream_t stream) {
    const float* X       = (const float*)d_in[0];   // [N, D]
    const float* C       = (const float*)d_in[1];   // [K, D]
    const int*   counts0 = (const int*)d_in[2];     // [K]
    float* out = (float*)d_out;

    // workspace layout
    char* p = (char*)d_ws;
    float*  seg     = (float*)p;          p += (size_t)K * D * 4;   // 4 MB (fallback / sort scratch)
    int*    cnt     = (int*)p;            p += (size_t)K * 4;       // 16 KB
    float*  c2      = (float*)p;          p += (size_t)K * 4;       // 16 KB
    double* lossAcc = (double*)p;         p += 16;
    size_t zero_all = (size_t)(p - (char*)d_ws);
    float*  cand    = (float*)p;          p += (size_t)N * 32 * 4;  // 8 MB (16 cands/row)
    unsigned short* Xh = (unsigned short*)p; p += (size_t)N * D * 2; // 32 MB
    unsigned short* Ch = (unsigned short*)p; p += (size_t)K * D * 2; //  2 MB
    size_t need = (size_t)(p - (char*)d_ws);                        // ~46 MB

    // sort scratch reuses the seg region (mfma path never touches seg)
    int* labInt    = (int*)seg;                  // N ints
    int* sortedIdx = labInt + N;                 // N ints
    int* offs      = sortedIdx + N;              // K ints
    int* cursor    = offs + K;                   // K ints

    if (ws_size >= need) {
        hipMemsetAsync(cnt, 0, (size_t)2 * K * 4 + 16, stream);  // cnt + c2 + lossAcc
        prep_c2<<<K, 64, 0, stream>>>(C, c2);
        convert_f16_both<<<(N*D/8 + K*D/8)/256, 256, 0, stream>>>(X, C, Xh, Ch, lossAcc);
        mfma_assign<<<dim3(N/128, 4), 256, 0, stream>>>(Xh, Ch, c2, cand);
        recheck_label<<<N/4, 256, 0, stream>>>(X, C, c2, cand, out, labInt, cnt);
        prefix_kernel<<<1, 64, 0, stream>>>(cnt, offs, cursor);
        scatter_idx<<<N/256, 256, 0, stream>>>(labInt, cursor, sortedIdx);
        center_update<<<K, 256, 0, stream>>>(X, C, counts0, cnt, offs, sortedIdx, lossAcc, out);
        loss_final<<<1, 1, 0, stream>>>(lossAcc, out);
    } else {
        hipMemsetAsync(d_ws, 0, zero_all, stream);
        prep_c2<<<K, 64, 0, stream>>>(C, c2);
        assign_fp32<<<N/128, 256, 0, stream>>>(X, C, c2, out, seg, cnt, lossAcc);
        finalize_kernel<<<(K*D)/256, 256, 0, stream>>>(C, counts0, seg, cnt, lossAcc, out);
    }
}

// Round 8
// 574.285 us; speedup vs baseline: 1.7037x; 1.7037x over previous
//
#include <hip/hip_runtime.h>
#include <cfloat>
#include <cstdint>

// Problem constants (fixed by the reference: N=65536, D=256, K=4096)
constexpr int N  = 65536;
constexpr int D  = 256;
constexpr int K  = 4096;

typedef __attribute__((ext_vector_type(8))) _Float16 half8;          // fp16x8 MFMA frag
typedef __attribute__((ext_vector_type(8))) unsigned short ushort8;  // 16B vector
typedef __attribute__((ext_vector_type(4))) float floatx4;

__device__ __forceinline__ floatx4 mfma_f16(half8 a, half8 b, floatx4 c) {
    return __builtin_amdgcn_mfma_f32_16x16x32_f16(a, b, c, 0, 0, 0);
}

// async global->LDS, 16B per lane; LDS dest = uniform base + lane*16 (m97 semantics)
__device__ __forceinline__ void ld_lds16(void* lds, const void* g) {
    __builtin_amdgcn_global_load_lds(
        (const __attribute__((address_space(1))) unsigned int*)g,
        (__attribute__((address_space(3))) unsigned int*)lds, 16, 0, 0);
}

// ---------------- c2[k] = sum_d C[k][d]^2 (exact fp32) ----------------
__global__ void prep_c2(const float* __restrict__ C, float* __restrict__ c2) {
    int k = blockIdx.x;
    int l = threadIdx.x;                 // 64 threads = 1 wave per center row
    const float4* row = (const float4*)(C + (size_t)k * D);
    float4 v = row[l];
    float s = v.x*v.x + v.y*v.y + v.z*v.z + v.w*v.w;
    #pragma unroll
    for (int m = 1; m < 64; m <<= 1) s += __shfl_xor(s, m);
    if (l == 0) c2[k] = s;
}

// -- fp32 -> fp16 (RTN), X and C in one launch; per-BLOCK sum(x^2) partial (NO atomics) --
__global__ void convert_f16_both(const float* __restrict__ X, const float* __restrict__ C,
                                 unsigned short* __restrict__ Xh,
                                 unsigned short* __restrict__ Ch,
                                 float* __restrict__ xsq_part) {
    __shared__ float red[4];
    int id = blockIdx.x * 256 + threadIdx.x;
    const int nX = N * D / 8;                     // 2097152; first 8192 blocks are pure X
    bool isX = id < nX;
    const float* src; unsigned short* dst;
    if (isX) { src = X; dst = Xh; }
    else     { src = C; dst = Ch; id -= nX; }
    const float4* s4 = (const float4*)src;
    float4 a = s4[2*id], b = s4[2*id+1];
    float xs[8] = {a.x,a.y,a.z,a.w,b.x,b.y,b.z,b.w};
    ushort8 h;
    float ps = 0.f;
    #pragma unroll
    for (int i = 0; i < 8; ++i) {
        union { _Float16 f; unsigned short u; } cv;
        cv.f = (_Float16)xs[i];
        h[i] = cv.u;
        ps += xs[i]*xs[i];
    }
    ((ushort8*)dst)[id] = h;
    if (isX) {   // blocks 0..8191 are pure-X: block-uniform branch
        #pragma unroll
        for (int m = 1; m < 64; m <<= 1) ps += __shfl_xor(ps, m);
        int t = threadIdx.x;
        if ((t & 63) == 0) red[t >> 6] = ps;
        __syncthreads();
        if (t == 0) xsq_part[blockIdx.x] = (red[0] + red[1]) + (red[2] + red[3]);
    }
}

// ---------------- fp16 MFMA GEMM + fused top-2 argmin ----------------
// Grid (N/128, 4): blockIdx.y = kb picks a 1024-center K-slice.
// A (128x256) staged ONCE via global_load_lds(16B); B double-buffered per
// 32-depth chunk, also global_load_lds. One barrier per chunk. LDS layout is
// lane-ordered (no pad); bank conflicts avoided by XOR depth-group swizzle
// applied on the GLOBAL address side: slot s holds group s ^ ((row>>1)&3).
// 256 thr = 4 waves (2x2), wave tile 64x64 = 4x4 frags 16x16x32 fp16.
// Score = c2[col] - 2*dot (x2 omitted: row-constant, argmin-invariant).
// Output: cand[row][h], h = 2*kb + wn in [0,8): (v1,idx1,v2,idx2) per 512-col group.
__global__ __launch_bounds__(256, 2) void mfma_assign(
        const unsigned short* __restrict__ Xh, const unsigned short* __restrict__ Ch,
        const float* __restrict__ c2, float* __restrict__ cand)
{
    __shared__ __align__(16) unsigned short sA[8*128*4*8];   // 64 KB: (dk,row,slot)x8h
    __shared__ __align__(16) unsigned short sB[2*128*4*8];   // 16 KB: (buf,row,slot)x8h

    const int t    = threadIdx.x;
    const int w    = t >> 6, l = t & 63;
    const int quad = l >> 4, lr = l & 15;
    const int wm   = w >> 1, wn = w & 1;
    const int rowbase = blockIdx.x * 128;
    const int kb   = blockIdx.y;                 // 0..3

    const int rl  = l >> 2;                      // staging local row (0..15)
    const int gsw = (l & 3) ^ ((l >> 3) & 3);    // swizzled depth-group to fetch

    // ---- stage B chunk 0 (ct = kb*8, dk = 0) into buf 0 ----
    #pragma unroll
    for (int k = 0; k < 2; ++k) {
        int q = 2*w + k;                                       // 0..7
        const unsigned short* gp = Ch + (size_t)(kb*1024 + q*16 + rl)*D + gsw*8;
        ld_lds16((char*)sB + q*1024, gp);
    }
    // ---- stage A: all 8 depth-chunks (64 calls, 16 per wave) ----
    #pragma unroll
    for (int k = 0; k < 16; ++k) {
        int q = w*16 + k;                                      // 0..63
        int c = q >> 3, rb = (q & 7) * 16;
        const unsigned short* gp = Xh + (size_t)(rowbase + rb + rl)*D + c*32 + gsw*8;
        ld_lds16((char*)sA + q*1024, gp);
    }

    // frag-read byte offsets (swizzle: slot = quad ^ ((lr>>1)&3); 2-way banks = free)
    const int sA_off = ((64*wm + lr)*4 + (quad ^ ((lr>>1)&3)))*16;
    const int sB_off = ((64*wn + lr)*4 + (quad ^ ((lr>>1)&3)))*16;

    // per-lane running top-2 per owned row (16 rows: st = 4*i + r)
    float v1[16], v2[16]; int x1[16], x2s[16];
    #pragma unroll
    for (int i = 0; i < 16; ++i) { v1[i]=FLT_MAX; v2[i]=FLT_MAX; x1[i]=0x7fffffff; x2s[i]=0x7fffffff; }

    floatx4 acc[4][4];
    float c2v[4]; int jidx[4];
    int buf = 0;

    for (int chunk = 0; chunk < 64; ++chunk) {
        const int dk = chunk & 7;
        const int ct = kb*8 + (chunk >> 3);

        if (dk == 0) {
            #pragma unroll
            for (int i = 0; i < 4; ++i)
                #pragma unroll
                for (int j = 0; j < 4; ++j) acc[i][j] = (floatx4)0.f;
            const int colbase = ct*128 + 64*wn;
            #pragma unroll
            for (int j = 0; j < 4; ++j) {
                int col = colbase + 16*j + lr;
                c2v[j] = c2[col]; jidx[j] = col;
            }
        }

        __syncthreads();   // drains this wave's global_load_lds (incl. this chunk's B)

        if (chunk < 63) {  // prefetch next B chunk into the other buffer
            int nc = chunk + 1;
            int nct = kb*8 + (nc >> 3), ndk = nc & 7;
            #pragma unroll
            for (int k = 0; k < 2; ++k) {
                int q = 2*w + k;
                const unsigned short* gp = Ch + (size_t)(nct*128 + q*16 + rl)*D + ndk*32 + gsw*8;
                ld_lds16((char*)sB + (buf^1)*8192 + q*1024, gp);
            }
        }

        half8 Af[4], Bf[4];
        #pragma unroll
        for (int i = 0; i < 4; ++i)
            Af[i] = *(const half8*)((const char*)sA + dk*8192 + i*1024 + sA_off);
        #pragma unroll
        for (int j = 0; j < 4; ++j)
            Bf[j] = *(const half8*)((const char*)sB + buf*8192 + j*1024 + sB_off);
        #pragma unroll
        for (int j = 0; j < 4; ++j)
            #pragma unroll
            for (int i = 0; i < 4; ++i)
                acc[i][j] = mfma_f16(Af[i], Bf[j], acc[i][j]);

        if (dk == 7) {
            // fused top-2 merge: rows st=4i+r (row=64wm+16i+4quad+r), cols jidx[j]
            #pragma unroll
            for (int i = 0; i < 4; ++i)
                #pragma unroll
                for (int j = 0; j < 4; ++j)
                    #pragma unroll
                    for (int r = 0; r < 4; ++r) {
                        float s = fmaf(-2.f, acc[i][j][r], c2v[j]);
                        int st = 4*i + r;
                        bool cA = s < v1[st];
                        bool cB = s < v2[st];
                        float tv = cB ? s : v2[st]; int tx = cB ? jidx[j] : x2s[st];
                        v2[st] = cA ? v1[st] : tv;  x2s[st] = cA ? x1[st] : tx;
                        v1[st] = cA ? s : v1[st];   x1[st]  = cA ? jidx[j] : x1[st];
                    }
        }
        buf ^= 1;
    }

    // final cross-lane (16 lr lanes) top-2 butterfly per owned row, then write
    #pragma unroll
    for (int i = 0; i < 4; ++i)
        #pragma unroll
        for (int r = 0; r < 4; ++r) {
            int st = 4*i + r;
            float a1 = v1[st], a2 = v2[st]; int ax1 = x1[st], ax2 = x2s[st];
            #pragma unroll
            for (int m = 1; m < 16; m <<= 1) {
                float b1f = __shfl_xor(a1, m); int bx1 = __shfl_xor(ax1, m);
                float b2f = __shfl_xor(a2, m); int bx2 = __shfl_xor(ax2, m);
                bool tt = (b1f < a1) || (b1f == a1 && bx1 < ax1);
                float n1 = tt ? b1f : a1; int nx1 = tt ? bx1 : ax1;
                float w1 = tt ? a1 : b1f; int wx1 = tt ? ax1 : bx1;  // loser of firsts
                float w2 = tt ? b2f : a2; int wx2 = tt ? bx2 : ax2;  // winner's second
                bool uu = (w2 < w1) || (w2 == w1 && wx2 < wx1);
                a1 = n1; ax1 = nx1;
                a2 = uu ? w2 : w1; ax2 = uu ? wx2 : wx1;
            }
            if (lr == 0) {
                int row = rowbase + 64*wm + 16*i + 4*quad + r;
                float4 o; o.x = a1; o.y = __int_as_float(ax1);
                o.z = a2; o.w = __int_as_float(ax2);
                ((float4*)cand)[(size_t)row*8 + 2*kb + wn] = o;
            }
        }
}

// ------- margin-gated exact recheck + labels + histogram (no loss here) ------
__global__ __launch_bounds__(256) void recheck_label(
        const float* __restrict__ X, const float* __restrict__ C,
        const float* __restrict__ c2, const float* __restrict__ cand,
        float* __restrict__ out_labels, int* __restrict__ labInt,
        int* __restrict__ cnt)
{
    int t = threadIdx.x, w = t >> 6, l = t & 63;
    int row = blockIdx.x * 4 + w;

    float s = FLT_MAX; int idx = 0x7fffffff;
    if (l < 16) {
        float4 e = ((const float4*)cand)[(size_t)row*8 + (l >> 1)];
        s   = (l & 1) ? e.z : e.x;
        idx = (l & 1) ? __float_as_int(e.w) : __float_as_int(e.y);
    }

    // global top-2 butterfly over the 16 candidate lanes (tie-break: smaller idx)
    float a1 = s, a2 = FLT_MAX; int ax1 = idx, ax2 = 0x7fffffff;
    #pragma unroll
    for (int m = 1; m < 16; m <<= 1) {
        float b1 = __shfl_xor(a1, m); int bx1 = __shfl_xor(ax1, m);
        float b2 = __shfl_xor(a2, m); int bx2 = __shfl_xor(ax2, m);
        bool tt = (b1 < a1) || (b1 == a1 && bx1 < ax1);
        float n1 = tt ? b1 : a1; int nx1 = tt ? bx1 : ax1;
        float w1 = tt ? a1 : b1; int wx1 = tt ? ax1 : bx1;
        float w2 = tt ? b2 : a2; int wx2 = tt ? bx2 : ax2;
        bool uu = (w2 < w1) || (w2 == w1 && wx2 < wx1);
        a1 = n1; ax1 = nx1;
        a2 = uu ? w2 : w1; ax2 = uu ? wx2 : wx1;
    }
    float s1 = __shfl(a1, 0), s2 = __shfl(a2, 0);
    int   i1 = __shfl(ax1, 0);

    int label;
    if (s2 - s1 > 0.25f) {          // wave-uniform fast path: no memory traffic
        label = i1;
    } else {
        float4 xv = ((const float4*)X)[(size_t)row*64 + l];
        float px = xv.x*xv.x + xv.y*xv.y + xv.z*xv.z + xv.w*xv.w;
        #pragma unroll
        for (int m = 1; m < 64; m <<= 1) px += __shfl_xor(px, m);
        bool active = (l < 16) && (s <= s1 + 0.25f);
        unsigned long long mask = __ballot(active);
        float best = FLT_MAX; int bi = 0x7fffffff;
        while (mask) {
            int k = __ffsll((long long)mask) - 1;
            mask &= mask - 1;
            int ck = __shfl(idx, k);
            float4 cv = ((const float4*)C)[(size_t)ck*64 + l];
            float pd = xv.x*cv.x + xv.y*cv.y + xv.z*cv.z + xv.w*cv.w;
            #pragma unroll
            for (int m = 1; m < 64; m <<= 1) pd += __shfl_xor(pd, m);
            float d2 = fmaf(-2.f, pd, px) + c2[ck];   // numpy's rounding order
            if (d2 < best || (d2 == best && ck < bi)) { best = d2; bi = ck; }
        }
        label = bi;
    }

    if (l == 0) {
        out_labels[row] = (float)label;
        labInt[row] = label;
        atomicAdd(&cnt[label], 1);
    }
}

// ---------------- exclusive prefix sum of the 4096-bin histogram -------------
__global__ void prefix_kernel(const int* __restrict__ cnt,
                              int* __restrict__ offs, int* __restrict__ cursor) {
    int l = threadIdx.x;                 // 64 lanes, 64 bins each
    int s = 0;
    #pragma unroll 8
    for (int i = 0; i < 64; ++i) s += cnt[l*64 + i];
    int inc = s;
    #pragma unroll
    for (int off = 1; off < 64; off <<= 1) {
        int u = __shfl_up(inc, off);
        if (l >= off) inc += u;
    }
    int run = inc - s;                   // exclusive lane base
    for (int i = 0; i < 64; ++i) {
        int k = l*64 + i;
        offs[k] = run; cursor[k] = run;
        run += cnt[k];
    }
}

// ---------------- bucket rows by label (one position atomic per row) ---------
__global__ void scatter_idx(const int* __restrict__ labInt,
                            int* __restrict__ cursor, int* __restrict__ sortedIdx) {
    int i = blockIdx.x * 256 + threadIdx.x;
    int lab = labInt[i];
    int pos = atomicAdd(&cursor[lab], 1);
    sortedIdx[pos] = i;
}

// -- atomic-free segment sum (block per center) + finalize + loss term store --
// loss = sum(x^2) [xsq_part] + sum_k (m_k*|c_k|^2 - 2*c_k.seg_k) [lossC, here]
__global__ __launch_bounds__(256) void center_update(
        const float* __restrict__ X, const float* __restrict__ C,
        const int* __restrict__ counts0, const int* __restrict__ cnt,
        const int* __restrict__ offs, const int* __restrict__ sortedIdx,
        float* __restrict__ lossC, float* __restrict__ out)
{
    __shared__ float red[4];
    int k = blockIdx.x, d = threadIdx.x;   // d = dim (D == 256 == blockDim)
    int start = offs[k], m = cnt[k];
    float acc = 0.f;
    int i = 0;
    for (; i + 4 <= m; i += 4) {
        int r0 = sortedIdx[start+i],   r1 = sortedIdx[start+i+1];
        int r2 = sortedIdx[start+i+2], r3 = sortedIdx[start+i+3];
        float a0 = X[(size_t)r0*D + d], a1 = X[(size_t)r1*D + d];
        float a2 = X[(size_t)r2*D + d], a3 = X[(size_t)r3*D + d];
        acc += (a0 + a1) + (a2 + a3);
    }
    for (; i < m; ++i) acc += X[(size_t)sortedIdx[start+i]*D + d];

    float cv = C[(size_t)k*D + d];
    float c0 = (float)counts0[k];
    out[N + (size_t)k*D + d] = (c0 * cv + acc) / (c0 + (float)m);
    if (d == 0) out[N + (size_t)K*D + k] = (float)(counts0[k] + m);

    // loss center-term: cv*(m*cv - 2*acc), reduced over d, plain store (no atomic)
    float lp = cv * fmaf((float)m, cv, -2.f*acc);
    #pragma unroll
    for (int s = 1; s < 64; s <<= 1) lp += __shfl_xor(lp, s);
    if ((d & 63) == 0) red[d >> 6] = lp;
    __syncthreads();
    if (d == 0) lossC[k] = (red[0] + red[1]) + (red[2] + red[3]);
}

// ---------------- final loss: reduce 8192 xsq partials + 4096 center terms ----
__global__ __launch_bounds__(256) void loss_final(
        const float* __restrict__ xsq_part, const float* __restrict__ lossC,
        float* __restrict__ out)
{
    __shared__ double red[4];
    int t = threadIdx.x;
    double s = 0.0;
    for (int i = t; i < 8192; i += 256) s += (double)xsq_part[i];
    for (int i = t; i < 4096; i += 256) s += (double)lossC[i];
    #pragma unroll
    for (int m = 1; m < 64; m <<= 1) s += __shfl_xor(s, m);
    if ((t & 63) == 0) red[t >> 6] = s;
    __syncthreads();
    if (t == 0)
        out[N + (size_t)K*D + K] = (float)(((red[0] + red[1]) + (red[2] + red[3])) / (double)N);
}

// ---------------- finalize (fallback path only) ----------------
__global__ void finalize_kernel(const float* __restrict__ C,
                                const int* __restrict__ counts0,
                                const float* __restrict__ seg,
                                const int* __restrict__ cnt,
                                const double* __restrict__ lossAcc,
                                float* __restrict__ out)
{
    int g = blockIdx.x * 256 + threadIdx.x;   // 0 .. K*D-1
    int k = g >> 8;                           // D = 256
    float c0 = (float)counts0[k];
    float m  = (float)cnt[k];
    out[N + g] = (c0 * C[g] + seg[g]) / (c0 + m);
    if (g < K) out[N + (size_t)K*D + g] = (float)(counts0[g] + cnt[g]);
    if (g == 0) out[N + (size_t)K*D + K] = (float)(lossAcc[0] / (double)N);
}

// ================= fallback (round-1 proven fp32 path, small ws) =============
__global__ __launch_bounds__(256, 2) void assign_fp32(
        const float* __restrict__ X, const float* __restrict__ C,
        const float* __restrict__ c2, float* __restrict__ out_labels,
        float* __restrict__ seg, int* __restrict__ cnt,
        double* __restrict__ lossAcc)
{
    constexpr int BM = 128, BN = 128, KD = 16;
    __shared__ float As[KD][BM];
    __shared__ float Bs[KD][BN];
    __shared__ float x2f[BM];
    __shared__ int   labs[BM];

    const int t  = threadIdx.x;
    const int tx = t & 15;
    const int ty = t >> 4;
    const int rowbase = blockIdx.x * BM;

    {
        int r  = t >> 1;
        int dh = (t & 1) * (D / 2);
        const float4* xr = (const float4*)(X + (size_t)(rowbase + r) * D + dh);
        float s = 0.f;
        #pragma unroll
        for (int i = 0; i < D / 8; ++i) {
            float4 v = xr[i];
            s += v.x*v.x + v.y*v.y + v.z*v.z + v.w*v.w;
        }
        s += __shfl_xor(s, 1);
        if ((t & 1) == 0) x2f[r] = s;
    }
    __syncthreads();

    float x2v[8];
    #pragma unroll
    for (int i = 0; i < 4; ++i) { x2v[i] = x2f[4*ty + i]; x2v[i+4] = x2f[64 + 4*ty + i]; }

    float rmv[8]; int rmi[8];
    #pragma unroll
    for (int i = 0; i < 8; ++i) { rmv[i] = FLT_MAX; rmi[i] = 0x7fffffff; }

    for (int ct = 0; ct < K / BN; ++ct) {
        float acc[8][8];
        #pragma unroll
        for (int i = 0; i < 8; ++i)
            #pragma unroll
            for (int j = 0; j < 8; ++j) acc[i][j] = 0.f;

        float c2f2[8];
        {
            float4 a = *(const float4*)(c2 + ct*BN + 4*tx);
            float4 b = *(const float4*)(c2 + ct*BN + 64 + 4*tx);
            c2f2[0]=a.x; c2f2[1]=a.y; c2f2[2]=a.z; c2f2[3]=a.w;
            c2f2[4]=b.x; c2f2[5]=b.y; c2f2[6]=b.z; c2f2[7]=b.w;
        }

        for (int dk = 0; dk < D / KD; ++dk) {
            #pragma unroll
            for (int i = 0; i < 2; ++i) {
                int f  = t + 256 * i;
                int r  = f >> 2;
                int dp = f & 3;
                float4 av = *(const float4*)(X + (size_t)(rowbase + r) * D + dk*KD + 4*dp);
                float4 bv = *(const float4*)(C + (size_t)(ct*BN + r) * D + dk*KD + 4*dp);
                As[4*dp+0][r]=av.x; As[4*dp+1][r]=av.y; As[4*dp+2][r]=av.z; As[4*dp+3][r]=av.w;
                Bs[4*dp+0][r]=bv.x; Bs[4*dp+1][r]=bv.y; Bs[4*dp+2][r]=bv.z; Bs[4*dp+3][r]=bv.w;
            }
            __syncthreads();
            #pragma unroll
            for (int kk = 0; kk < KD; ++kk) {
                float4 a0 = *(const float4*)&As[kk][4*ty];
                float4 a1 = *(const float4*)&As[kk][64 + 4*ty];
                float4 b0 = *(const float4*)&Bs[kk][4*tx];
                float4 b1 = *(const float4*)&Bs[kk][64 + 4*tx];
                float av[8] = {a0.x,a0.y,a0.z,a0.w,a1.x,a1.y,a1.z,a1.w};
                float bv[8] = {b0.x,b0.y,b0.z,b0.w,b1.x,b1.y,b1.z,b1.w};
                #pragma unroll
                for (int i = 0; i < 8; ++i)
                    #pragma unroll
                    for (int j = 0; j < 8; ++j)
                        acc[i][j] = fmaf(av[i], bv[j], acc[i][j]);
            }
            __syncthreads();
        }

        #pragma unroll
        for (int i = 0; i < 8; ++i) {
            float bv = FLT_MAX; int bi = 0x7fffffff;
            #pragma unroll
            for (int j = 0; j < 8; ++j) {
                int coll = (j < 4) ? (4*tx + j) : (64 + 4*tx + (j - 4));
                float v = fmaf(-2.f, acc[i][j], x2v[i]) + c2f2[j];
                int idx = ct * BN + coll;
                if (v < bv || (v == bv && idx < bi)) { bv = v; bi = idx; }
            }
            #pragma unroll
            for (int m = 1; m < 16; m <<= 1) {
                float ov = __shfl_xor(bv, m);
                int   oi = __shfl_xor(bi, m);
                if (ov < bv || (ov == bv && oi < bi)) { bv = ov; bi = oi; }
            }
            if (bv < rmv[i] || (bv == rmv[i] && bi < rmi[i])) { rmv[i] = bv; rmi[i] = bi; }
        }
    }

    if (tx == 0) {
        #pragma unroll
        for (int i = 0; i < 8; ++i) {
            int r = (i < 4) ? (4*ty + i) : (64 + 4*ty + (i - 4));
            labs[r] = rmi[i];
            out_labels[rowbase + r] = (float)rmi[i];
            atomicAdd(&cnt[rmi[i]], 1);
        }
    }
    __syncthreads();

    {
        int r   = t >> 1;
        int dh  = (t & 1) * (D / 2);
        int lab = labs[r];
        const float4* xr = (const float4*)(X + (size_t)(rowbase + r) * D + dh);
        const float4* cr = (const float4*)(C + (size_t)lab * D + dh);
        float* sp = seg + (size_t)lab * D + dh;
        float ls = 0.f;
        #pragma unroll 8
        for (int i = 0; i < D / 8; ++i) {
            float4 xv = xr[i];
            float4 cv = cr[i];
            atomicAdd(sp + 4*i + 0, xv.x);
            atomicAdd(sp + 4*i + 1, xv.y);
            atomicAdd(sp + 4*i + 2, xv.z);
            atomicAdd(sp + 4*i + 3, xv.w);
            float d0 = xv.x - cv.x, d1 = xv.y - cv.y;
            float d2 = xv.z - cv.z, d3 = xv.w - cv.w;
            ls += d0*d0 + d1*d1 + d2*d2 + d3*d3;
        }
        #pragma unroll
        for (int m = 1; m < 64; m <<= 1) ls += __shfl_xor(ls, m);
        if ((t & 63) == 0) atomicAdd(lossAcc, (double)ls);
    }
}

extern "C" void kernel_launch(void* const* d_in, const int* in_sizes, int n_in,
                              void* d_out, int out_size, void* d_ws, size_t ws_size,
                              hipStream_t stream) {
    const float* X       = (const float*)d_in[0];   // [N, D]
    const float* C       = (const float*)d_in[1];   // [K, D]
    const int*   counts0 = (const int*)d_in[2];     // [K]
    float* out = (float*)d_out;

    // workspace layout
    char* p = (char*)d_ws;
    float*  seg     = (float*)p;          p += (size_t)K * D * 4;   // 4 MB (fallback / sort scratch)
    int*    cnt     = (int*)p;            p += (size_t)K * 4;       // 16 KB
    float*  c2      = (float*)p;          p += (size_t)K * 4;       // 16 KB
    double* lossAcc = (double*)p;         p += 16;
    size_t zero_all = (size_t)(p - (char*)d_ws);
    float*  cand    = (float*)p;          p += (size_t)N * 32 * 4;  // 8 MB (16 cands/row)
    unsigned short* Xh = (unsigned short*)p; p += (size_t)N * D * 2; // 32 MB
    unsigned short* Ch = (unsigned short*)p; p += (size_t)K * D * 2; //  2 MB
    float* xsq_part = (float*)p;          p += 8192 * 4;            // 32 KB
    float* lossC    = (float*)p;          p += (size_t)K * 4;       // 16 KB
    size_t need = (size_t)(p - (char*)d_ws);                        // ~46 MB

    // sort scratch reuses the seg region (mfma path never touches seg)
    int* labInt    = (int*)seg;                  // N ints
    int* sortedIdx = labInt + N;                 // N ints
    int* offs      = sortedIdx + N;              // K ints
    int* cursor    = offs + K;                   // K ints

    if (ws_size >= need) {
        hipMemsetAsync(cnt, 0, (size_t)K * 4, stream);  // histogram only
        prep_c2<<<K, 64, 0, stream>>>(C, c2);
        convert_f16_both<<<(N*D/8 + K*D/8)/256, 256, 0, stream>>>(X, C, Xh, Ch, xsq_part);
        mfma_assign<<<dim3(N/128, 4), 256, 0, stream>>>(Xh, Ch, c2, cand);
        recheck_label<<<N/4, 256, 0, stream>>>(X, C, c2, cand, out, labInt, cnt);
        prefix_kernel<<<1, 64, 0, stream>>>(cnt, offs, cursor);
        scatter_idx<<<N/256, 256, 0, stream>>>(labInt, cursor, sortedIdx);
        center_update<<<K, 256, 0, stream>>>(X, C, counts0, cnt, offs, sortedIdx, lossC, out);
        loss_final<<<1, 256, 0, stream>>>(xsq_part, lossC, out);
    } else {
        hipMemsetAsync(d_ws, 0, zero_all, stream);
        prep_c2<<<K, 64, 0, stream>>>(C, c2);
        assign_fp32<<<N/128, 256, 0, stream>>>(X, C, c2, out, seg, cnt, lossAcc);
        finalize_kernel<<<(K*D)/256, 256, 0, stream>>>(C, counts0, seg, cnt, lossAcc, out);
    }
}

// Round 9
// 571.987 us; speedup vs baseline: 1.7105x; 1.0040x over previous
//
#include <hip/hip_runtime.h>
#include <cfloat>
#include <cstdint>

// Problem constants (fixed by the reference: N=65536, D=256, K=4096)
constexpr int N  = 65536;
constexpr int D  = 256;
constexpr int K  = 4096;

typedef __attribute__((ext_vector_type(8))) _Float16 half8;          // fp16x8 MFMA frag
typedef __attribute__((ext_vector_type(8))) unsigned short ushort8;  // 16B vector
typedef __attribute__((ext_vector_type(4))) float floatx4;

__device__ __forceinline__ floatx4 mfma_f16(half8 a, half8 b, floatx4 c) {
    return __builtin_amdgcn_mfma_f32_16x16x32_f16(a, b, c, 0, 0, 0);
}

// async global->LDS, 16B per lane; LDS dest = uniform base + lane*16 (m97 semantics)
__device__ __forceinline__ void ld_lds16(void* lds, const void* g) {
    __builtin_amdgcn_global_load_lds(
        (const __attribute__((address_space(1))) unsigned int*)g,
        (__attribute__((address_space(3))) unsigned int*)lds, 16, 0, 0);
}

// ---------------- c2[k] = sum_d C[k][d]^2 (fallback path only) ----------------
__global__ void prep_c2(const float* __restrict__ C, float* __restrict__ c2) {
    int k = blockIdx.x;
    int l = threadIdx.x;
    const float4* row = (const float4*)(C + (size_t)k * D);
    float4 v = row[l];
    float s = v.x*v.x + v.y*v.y + v.z*v.z + v.w*v.w;
    #pragma unroll
    for (int m = 1; m < 64; m <<= 1) s += __shfl_xor(s, m);
    if (l == 0) c2[k] = s;
}

// -- fp32 -> fp16 (RTN), X and C in one launch; per-BLOCK sum(x^2) partials and
// fused c2 (sum of C row squares) -- no hot atomics anywhere.
__global__ void convert_f16_both(const float* __restrict__ X, const float* __restrict__ C,
                                 unsigned short* __restrict__ Xh,
                                 unsigned short* __restrict__ Ch,
                                 float* __restrict__ xsq_part,
                                 float* __restrict__ c2) {
    __shared__ float red[4];
    int id = blockIdx.x * 256 + threadIdx.x;
    const int nX = N * D / 8;                     // first 8192 blocks are pure X
    bool isX = id < nX;
    const float* src; unsigned short* dst;
    if (isX) { src = X; dst = Xh; }
    else     { src = C; dst = Ch; id -= nX; }
    const float4* s4 = (const float4*)src;
    float4 a = s4[2*id], b = s4[2*id+1];
    float xs[8] = {a.x,a.y,a.z,a.w,b.x,b.y,b.z,b.w};
    ushort8 h;
    float ps = 0.f;
    #pragma unroll
    for (int i = 0; i < 8; ++i) {
        union { _Float16 f; unsigned short u; } cv;
        cv.f = (_Float16)xs[i];
        h[i] = cv.u;
        ps += xs[i]*xs[i];
    }
    ((ushort8*)dst)[id] = h;
    int t = threadIdx.x;
    if (isX) {   // block-uniform branch: per-block partial of sum(x^2)
        #pragma unroll
        for (int m = 1; m < 64; m <<= 1) ps += __shfl_xor(ps, m);
        if ((t & 63) == 0) red[t >> 6] = ps;
        __syncthreads();
        if (t == 0) xsq_part[blockIdx.x] = (red[0] + red[1]) + (red[2] + red[3]);
    } else {     // C rows: 32 consecutive threads cover one row (D=256 = 32*8)
        #pragma unroll
        for (int m = 1; m < 32; m <<= 1) ps += __shfl_xor(ps, m);
        if ((t & 31) == 0) c2[id >> 5] = ps;
    }
}

// ---------------- fp16 MFMA GEMM + fused top-2 argmin ----------------
// Grid (N/128, 4): blockIdx.y = kb picks a 1024-center K-slice.
// A (128x256) staged ONCE via global_load_lds(16B); B double-buffered per
// 32-depth chunk, also global_load_lds, running-pointer addressing. One
// barrier per chunk. Bank conflicts avoided by XOR depth-group swizzle on the
// GLOBAL side. 256 thr = 4 waves (2x2), wave tile 64x64 = 4x4 frags 16x16x32.
// Score = c2[col] - 2*dot (x2 omitted: row-constant, argmin-invariant).
// Output: cand[row][h], h = 2*kb + wn in [0,8): (v1,idx1,v2,idx2) per 512-col group.
__global__ __launch_bounds__(256, 2) void mfma_assign(
        const unsigned short* __restrict__ Xh, const unsigned short* __restrict__ Ch,
        const float* __restrict__ c2, float* __restrict__ cand)
{
    __shared__ __align__(16) unsigned short sA[8*128*4*8];   // 64 KB: (dk,row,slot)x8h
    __shared__ __align__(16) unsigned short sB[2*128*4*8];   // 16 KB: (buf,row,slot)x8h

    const int t    = threadIdx.x;
    const int w    = t >> 6, l = t & 63;
    const int quad = l >> 4, lr = l & 15;
    const int wm   = w >> 1, wn = w & 1;
    const int rowbase = blockIdx.x * 128;
    const int kb   = blockIdx.y;                 // 0..3

    const int rl  = l >> 2;                      // staging local row (0..15)
    const int gsw = (l & 3) ^ ((l >> 3) & 3);    // swizzled depth-group to fetch

    // ---- stage B chunk 0 (ct = kb*8, dk = 0) into buf 0 ----
    #pragma unroll
    for (int k = 0; k < 2; ++k) {
        int q = 2*w + k;                                       // 0..7
        const unsigned short* gp = Ch + (size_t)(kb*1024 + q*16 + rl)*D + gsw*8;
        ld_lds16((char*)sB + q*1024, gp);
    }
    // ---- stage A: all 8 depth-chunks (64 calls, 16 per wave) ----
    #pragma unroll
    for (int k = 0; k < 16; ++k) {
        int q = w*16 + k;                                      // 0..63
        int c = q >> 3, rb = (q & 7) * 16;
        const unsigned short* gp = Xh + (size_t)(rowbase + rb + rl)*D + c*32 + gsw*8;
        ld_lds16((char*)sA + q*1024, gp);
    }

    // running prefetch pointer for B (next chunk = nc, starting at nc=1):
    // addr(nc) = Ch + (ct(nc)*128 + 2w*16 + rl)*D + ndk*32 + gsw*8
    const unsigned short* gpB = Ch + (size_t)(kb*1024 + 2*w*16 + rl)*D + gsw*8 + 32;

    // frag-read byte offsets (swizzle: slot = quad ^ ((lr>>1)&3); 2-way banks = free)
    const int sA_off = ((64*wm + lr)*4 + (quad ^ ((lr>>1)&3)))*16;
    const int sB_off = ((64*wn + lr)*4 + (quad ^ ((lr>>1)&3)))*16;

    // per-lane running top-2 per owned row (16 rows: st = 4*i + r)
    float v1[16], v2[16]; int x1[16], x2s[16];
    #pragma unroll
    for (int i = 0; i < 16; ++i) { v1[i]=FLT_MAX; v2[i]=FLT_MAX; x1[i]=0x7fffffff; x2s[i]=0x7fffffff; }

    floatx4 acc[4][4];
    float c2v[4]; int jidx[4];
    int buf = 0;

    for (int chunk = 0; chunk < 64; ++chunk) {
        const int dk = chunk & 7;
        const int ct = kb*8 + (chunk >> 3);

        if (dk == 0) {
            #pragma unroll
            for (int i = 0; i < 4; ++i)
                #pragma unroll
                for (int j = 0; j < 4; ++j) acc[i][j] = (floatx4)0.f;
            const int colbase = ct*128 + 64*wn;
            #pragma unroll
            for (int j = 0; j < 4; ++j) {
                int col = colbase + 16*j + lr;
                c2v[j] = c2[col]; jidx[j] = col;
            }
        }

        __syncthreads();   // drains this wave's global_load_lds (incl. this chunk's B)

        if (chunk < 63) {  // prefetch next B chunk into the other buffer
            int nc = chunk + 1;
            ld_lds16((char*)sB + (buf^1)*8192 + (2*w+0)*1024, gpB);
            ld_lds16((char*)sB + (buf^1)*8192 + (2*w+1)*1024, gpB + 16*D);
            gpB += ((nc & 7) == 7) ? (size_t)(128*D - 7*32) : 32;
        }

        half8 Af[4], Bf[4];
        #pragma unroll
        for (int i = 0; i < 4; ++i)
            Af[i] = *(const half8*)((const char*)sA + dk*8192 + i*1024 + sA_off);
        #pragma unroll
        for (int j = 0; j < 4; ++j)
            Bf[j] = *(const half8*)((const char*)sB + buf*8192 + j*1024 + sB_off);
        #pragma unroll
        for (int j = 0; j < 4; ++j)
            #pragma unroll
            for (int i = 0; i < 4; ++i)
                acc[i][j] = mfma_f16(Af[i], Bf[j], acc[i][j]);

        if (dk == 7) {
            // fused top-2 merge: rows st=4i+r (row=64wm+16i+4quad+r), cols jidx[j]
            #pragma unroll
            for (int i = 0; i < 4; ++i)
                #pragma unroll
                for (int j = 0; j < 4; ++j)
                    #pragma unroll
                    for (int r = 0; r < 4; ++r) {
                        float s = fmaf(-2.f, acc[i][j][r], c2v[j]);
                        int st = 4*i + r;
                        bool cA = s < v1[st];
                        bool cB = s < v2[st];
                        float tv = cB ? s : v2[st]; int tx = cB ? jidx[j] : x2s[st];
                        v2[st] = cA ? v1[st] : tv;  x2s[st] = cA ? x1[st] : tx;
                        v1[st] = cA ? s : v1[st];   x1[st]  = cA ? jidx[j] : x1[st];
                    }
        }
        buf ^= 1;
    }

    // final cross-lane (16 lr lanes) top-2 butterfly per owned row, then write
    #pragma unroll
    for (int i = 0; i < 4; ++i)
        #pragma unroll
        for (int r = 0; r < 4; ++r) {
            int st = 4*i + r;
            float a1 = v1[st], a2 = v2[st]; int ax1 = x1[st], ax2 = x2s[st];
            #pragma unroll
            for (int m = 1; m < 16; m <<= 1) {
                float b1f = __shfl_xor(a1, m); int bx1 = __shfl_xor(ax1, m);
                float b2f = __shfl_xor(a2, m); int bx2 = __shfl_xor(ax2, m);
                bool tt = (b1f < a1) || (b1f == a1 && bx1 < ax1);
                float n1 = tt ? b1f : a1; int nx1 = tt ? bx1 : ax1;
                float w1 = tt ? a1 : b1f; int wx1 = tt ? ax1 : bx1;  // loser of firsts
                float w2 = tt ? b2f : a2; int wx2 = tt ? bx2 : ax2;  // winner's second
                bool uu = (w2 < w1) || (w2 == w1 && wx2 < wx1);
                a1 = n1; ax1 = nx1;
                a2 = uu ? w2 : w1; ax2 = uu ? wx2 : wx1;
            }
            if (lr == 0) {
                int row = rowbase + 64*wm + 16*i + 4*quad + r;
                float4 o; o.x = a1; o.y = __int_as_float(ax1);
                o.z = a2; o.w = __int_as_float(ax2);
                ((float4*)cand)[(size_t)row*8 + 2*kb + wn] = o;
            }
        }
}

// ------- margin-gated exact recheck + labels + histogram, 4 rows per wave ------
// Lanes split into 4 groups of 16; group g owns row 4*waverow+g. One butterfly
// serves all 4 rows. Certain groups (margin > 0.25) write immediately with no
// memory traffic; uncertain rows (rare) are handled whole-wave sequentially.
__global__ __launch_bounds__(256) void recheck_label(
        const float* __restrict__ X, const float* __restrict__ C,
        const float* __restrict__ c2, const float* __restrict__ cand,
        float* __restrict__ out_labels, int* __restrict__ labInt,
        int* __restrict__ cnt)
{
    int t = threadIdx.x, w = t >> 6, l = t & 63;
    int g  = l >> 4;                       // row-group within wave
    int lr = l & 15;
    int row0 = (blockIdx.x * 4 + w) * 4;   // 4 rows per wave
    int row  = row0 + g;

    // lane lr of group g holds candidate lr of its row
    float4 e = ((const float4*)cand)[(size_t)row*8 + (lr >> 1)];
    float s  = (lr & 1) ? e.z : e.x;
    int  idx = (lr & 1) ? __float_as_int(e.w) : __float_as_int(e.y);

    // top-2 butterfly within each 16-lane group (all lanes end with group result)
    float a1 = s, a2 = FLT_MAX; int ax1 = idx, ax2 = 0x7fffffff;
    #pragma unroll
    for (int m = 1; m < 16; m <<= 1) {
        float b1 = __shfl_xor(a1, m); int bx1 = __shfl_xor(ax1, m);
        float b2 = __shfl_xor(a2, m); int bx2 = __shfl_xor(ax2, m);
        bool tt = (b1 < a1) || (b1 == a1 && bx1 < ax1);
        float n1 = tt ? b1 : a1; int nx1 = tt ? bx1 : ax1;
        float w1 = tt ? a1 : b1; int wx1 = tt ? ax1 : bx1;
        float w2 = tt ? b2 : a2; int wx2 = tt ? bx2 : ax2;
        bool uu = (w2 < w1) || (w2 == w1 && wx2 < wx1);
        a1 = n1; ax1 = nx1;
        a2 = uu ? w2 : w1; ax2 = uu ? wx2 : wx1;
    }

    bool certain = (a2 - a1 > 0.25f);               // group-uniform
    unsigned long long certMask = __ballot(certain);

    // fast path: certain groups store now (no X/C traffic)
    if (certain && lr == 0) {
        out_labels[row] = (float)ax1;
        labInt[row] = ax1;
        atomicAdd(&cnt[ax1], 1);
    }

    // slow path: whole wave processes each uncertain row sequentially
    #pragma unroll
    for (int q = 0; q < 4; ++q) {
        if ((certMask >> (q*16)) & 1ull) continue;   // wave-uniform test
        int r = row0 + q;
        float sq  = __shfl(s,   q*16 + lr);          // group q's candidates -> lanes 0..15
        int   iq  = __shfl(idx, q*16 + lr);
        float gs1 = __shfl(a1,  q*16);

        float4 xv = ((const float4*)X)[(size_t)r*64 + l];
        float px = xv.x*xv.x + xv.y*xv.y + xv.z*xv.z + xv.w*xv.w;
        #pragma unroll
        for (int m = 1; m < 64; m <<= 1) px += __shfl_xor(px, m);

        bool active = (l < 16) && (sq <= gs1 + 0.25f);
        unsigned long long mask = __ballot(active);
        float best = FLT_MAX; int bi = 0x7fffffff;
        while (mask) {
            int k = __ffsll((long long)mask) - 1;
            mask &= mask - 1;
            int ck = __shfl(iq, k);
            float4 cv = ((const float4*)C)[(size_t)ck*64 + l];
            float pd = xv.x*cv.x + xv.y*cv.y + xv.z*cv.z + xv.w*cv.w;
            #pragma unroll
            for (int m = 1; m < 64; m <<= 1) pd += __shfl_xor(pd, m);
            float d2 = fmaf(-2.f, pd, px) + c2[ck];   // numpy's rounding order
            if (d2 < best || (d2 == best && ck < bi)) { best = d2; bi = ck; }
        }
        if (l == 0) {
            out_labels[r] = (float)bi;
            labInt[r] = bi;
            atomicAdd(&cnt[bi], 1);
        }
    }
}

// ---------------- exclusive prefix sum of the 4096-bin histogram -------------
__global__ void prefix_kernel(const int* __restrict__ cnt,
                              int* __restrict__ offs, int* __restrict__ cursor) {
    int l = threadIdx.x;                 // 64 lanes, 64 bins each
    int s = 0;
    #pragma unroll 8
    for (int i = 0; i < 64; ++i) s += cnt[l*64 + i];
    int inc = s;
    #pragma unroll
    for (int off = 1; off < 64; off <<= 1) {
        int u = __shfl_up(inc, off);
        if (l >= off) inc += u;
    }
    int run = inc - s;                   // exclusive lane base
    for (int i = 0; i < 64; ++i) {
        int k = l*64 + i;
        offs[k] = run; cursor[k] = run;
        run += cnt[k];
    }
}

// ---------------- bucket rows by label (one position atomic per row) ---------
__global__ void scatter_idx(const int* __restrict__ labInt,
                            int* __restrict__ cursor, int* __restrict__ sortedIdx) {
    int i = blockIdx.x * 256 + threadIdx.x;
    int lab = labInt[i];
    int pos = atomicAdd(&cursor[lab], 1);
    sortedIdx[pos] = i;
}

// -- atomic-free segment sum (block per center) + finalize + loss term store --
// loss = sum(x^2) [xsq_part] + sum_k (m_k*|c_k|^2 - 2*c_k.seg_k) [lossC, here]
__global__ __launch_bounds__(256) void center_update(
        const float* __restrict__ X, const float* __restrict__ C,
        const int* __restrict__ counts0, const int* __restrict__ cnt,
        const int* __restrict__ offs, const int* __restrict__ sortedIdx,
        float* __restrict__ lossC, float* __restrict__ out)
{
    __shared__ float red[4];
    int k = blockIdx.x, d = threadIdx.x;   // d = dim (D == 256 == blockDim)
    int start = offs[k], m = cnt[k];
    float acc = 0.f;
    int i = 0;
    for (; i + 4 <= m; i += 4) {
        int r0 = sortedIdx[start+i],   r1 = sortedIdx[start+i+1];
        int r2 = sortedIdx[start+i+2], r3 = sortedIdx[start+i+3];
        float a0 = X[(size_t)r0*D + d], a1 = X[(size_t)r1*D + d];
        float a2 = X[(size_t)r2*D + d], a3 = X[(size_t)r3*D + d];
        acc += (a0 + a1) + (a2 + a3);
    }
    for (; i < m; ++i) acc += X[(size_t)sortedIdx[start+i]*D + d];

    float cv = C[(size_t)k*D + d];
    float c0 = (float)counts0[k];
    out[N + (size_t)k*D + d] = (c0 * cv + acc) / (c0 + (float)m);
    if (d == 0) out[N + (size_t)K*D + k] = (float)(counts0[k] + m);

    // loss center-term: cv*(m*cv - 2*acc), reduced over d, plain store (no atomic)
    float lp = cv * fmaf((float)m, cv, -2.f*acc);
    #pragma unroll
    for (int s = 1; s < 64; s <<= 1) lp += __shfl_xor(lp, s);
    if ((d & 63) == 0) red[d >> 6] = lp;
    __syncthreads();
    if (d == 0) lossC[k] = (red[0] + red[1]) + (red[2] + red[3]);
}

// ---------------- final loss: reduce 8192 xsq partials + 4096 center terms ----
__global__ __launch_bounds__(256) void loss_final(
        const float* __restrict__ xsq_part, const float* __restrict__ lossC,
        float* __restrict__ out)
{
    __shared__ double red[4];
    int t = threadIdx.x;
    double s = 0.0;
    for (int i = t; i < 8192; i += 256) s += (double)xsq_part[i];
    for (int i = t; i < 4096; i += 256) s += (double)lossC[i];
    #pragma unroll
    for (int m = 1; m < 64; m <<= 1) s += __shfl_xor(s, m);
    if ((t & 63) == 0) red[t >> 6] = s;
    __syncthreads();
    if (t == 0)
        out[N + (size_t)K*D + K] = (float)(((red[0] + red[1]) + (red[2] + red[3])) / (double)N);
}

// ---------------- finalize (fallback path only) ----------------
__global__ void finalize_kernel(const float* __restrict__ C,
                                const int* __restrict__ counts0,
                                const float* __restrict__ seg,
                                const int* __restrict__ cnt,
                                const double* __restrict__ lossAcc,
                                float* __restrict__ out)
{
    int g = blockIdx.x * 256 + threadIdx.x;   // 0 .. K*D-1
    int k = g >> 8;                           // D = 256
    float c0 = (float)counts0[k];
    float m  = (float)cnt[k];
    out[N + g] = (c0 * C[g] + seg[g]) / (c0 + m);
    if (g < K) out[N + (size_t)K*D + g] = (float)(counts0[g] + cnt[g]);
    if (g == 0) out[N + (size_t)K*D + K] = (float)(lossAcc[0] / (double)N);
}

// ================= fallback (round-1 proven fp32 path, small ws) =============
__global__ __launch_bounds__(256, 2) void assign_fp32(
        const float* __restrict__ X, const float* __restrict__ C,
        const float* __restrict__ c2, float* __restrict__ out_labels,
        float* __restrict__ seg, int* __restrict__ cnt,
        double* __restrict__ lossAcc)
{
    constexpr int BM = 128, BN = 128, KD = 16;
    __shared__ float As[KD][BM];
    __shared__ float Bs[KD][BN];
    __shared__ float x2f[BM];
    __shared__ int   labs[BM];

    const int t  = threadIdx.x;
    const int tx = t & 15;
    const int ty = t >> 4;
    const int rowbase = blockIdx.x * BM;

    {
        int r  = t >> 1;
        int dh = (t & 1) * (D / 2);
        const float4* xr = (const float4*)(X + (size_t)(rowbase + r) * D + dh);
        float s = 0.f;
        #pragma unroll
        for (int i = 0; i < D / 8; ++i) {
            float4 v = xr[i];
            s += v.x*v.x + v.y*v.y + v.z*v.z + v.w*v.w;
        }
        s += __shfl_xor(s, 1);
        if ((t & 1) == 0) x2f[r] = s;
    }
    __syncthreads();

    float x2v[8];
    #pragma unroll
    for (int i = 0; i < 4; ++i) { x2v[i] = x2f[4*ty + i]; x2v[i+4] = x2f[64 + 4*ty + i]; }

    float rmv[8]; int rmi[8];
    #pragma unroll
    for (int i = 0; i < 8; ++i) { rmv[i] = FLT_MAX; rmi[i] = 0x7fffffff; }

    for (int ct = 0; ct < K / BN; ++ct) {
        float acc[8][8];
        #pragma unroll
        for (int i = 0; i < 8; ++i)
            #pragma unroll
            for (int j = 0; j < 8; ++j) acc[i][j] = 0.f;

        float c2f2[8];
        {
            float4 a = *(const float4*)(c2 + ct*BN + 4*tx);
            float4 b = *(const float4*)(c2 + ct*BN + 64 + 4*tx);
            c2f2[0]=a.x; c2f2[1]=a.y; c2f2[2]=a.z; c2f2[3]=a.w;
            c2f2[4]=b.x; c2f2[5]=b.y; c2f2[6]=b.z; c2f2[7]=b.w;
        }

        for (int dk = 0; dk < D / KD; ++dk) {
            #pragma unroll
            for (int i = 0; i < 2; ++i) {
                int f  = t + 256 * i;
                int r  = f >> 2;
                int dp = f & 3;
                float4 av = *(const float4*)(X + (size_t)(rowbase + r) * D + dk*KD + 4*dp);
                float4 bv = *(const float4*)(C + (size_t)(ct*BN + r) * D + dk*KD + 4*dp);
                As[4*dp+0][r]=av.x; As[4*dp+1][r]=av.y; As[4*dp+2][r]=av.z; As[4*dp+3][r]=av.w;
                Bs[4*dp+0][r]=bv.x; Bs[4*dp+1][r]=bv.y; Bs[4*dp+2][r]=bv.z; Bs[4*dp+3][r]=bv.w;
            }
            __syncthreads();
            #pragma unroll
            for (int kk = 0; kk < KD; ++kk) {
                float4 a0 = *(const float4*)&As[kk][4*ty];
                float4 a1 = *(const float4*)&As[kk][64 + 4*ty];
                float4 b0 = *(const float4*)&Bs[kk][4*tx];
                float4 b1 = *(const float4*)&Bs[kk][64 + 4*tx];
                float av[8] = {a0.x,a0.y,a0.z,a0.w,a1.x,a1.y,a1.z,a1.w};
                float bv[8] = {b0.x,b0.y,b0.z,b0.w,b1.x,b1.y,b1.z,b1.w};
                #pragma unroll
                for (int i = 0; i < 8; ++i)
                    #pragma unroll
                    for (int j = 0; j < 8; ++j)
                        acc[i][j] = fmaf(av[i], bv[j], acc[i][j]);
            }
            __syncthreads();
        }

        #pragma unroll
        for (int i = 0; i < 8; ++i) {
            float bv = FLT_MAX; int bi = 0x7fffffff;
            #pragma unroll
            for (int j = 0; j < 8; ++j) {
                int coll = (j < 4) ? (4*tx + j) : (64 + 4*tx + (j - 4));
                float v = fmaf(-2.f, acc[i][j], x2v[i]) + c2f2[j];
                int idx = ct * BN + coll;
                if (v < bv || (v == bv && idx < bi)) { bv = v; bi = idx; }
            }
            #pragma unroll
            for (int m = 1; m < 16; m <<= 1) {
                float ov = __shfl_xor(bv, m);
                int   oi = __shfl_xor(bi, m);
                if (ov < bv || (ov == bv && oi < bi)) { bv = ov; bi = oi; }
            }
            if (bv < rmv[i] || (bv == rmv[i] && bi < rmi[i])) { rmv[i] = bv; rmi[i] = bi; }
        }
    }

    if (tx == 0) {
        #pragma unroll
        for (int i = 0; i < 8; ++i) {
            int r = (i < 4) ? (4*ty + i) : (64 + 4*ty + (i - 4));
            labs[r] = rmi[i];
            out_labels[rowbase + r] = (float)rmi[i];
            atomicAdd(&cnt[rmi[i]], 1);
        }
    }
    __syncthreads();

    {
        int r   = t >> 1;
        int dh  = (t & 1) * (D / 2);
        int lab = labs[r];
        const float4* xr = (const float4*)(X + (size_t)(rowbase + r) * D + dh);
        const float4* cr = (const float4*)(C + (size_t)lab * D + dh);
        float* sp = seg + (size_t)lab * D + dh;
        float ls = 0.f;
        #pragma unroll 8
        for (int i = 0; i < D / 8; ++i) {
            float4 xv = xr[i];
            float4 cv = cr[i];
            atomicAdd(sp + 4*i + 0, xv.x);
            atomicAdd(sp + 4*i + 1, xv.y);
            atomicAdd(sp + 4*i + 2, xv.z);
            atomicAdd(sp + 4*i + 3, xv.w);
            float d0 = xv.x - cv.x, d1 = xv.y - cv.y;
            float d2 = xv.z - cv.z, d3 = xv.w - cv.w;
            ls += d0*d0 + d1*d1 + d2*d2 + d3*d3;
        }
        #pragma unroll
        for (int m = 1; m < 64; m <<= 1) ls += __shfl_xor(ls, m);
        if ((t & 63) == 0) atomicAdd(lossAcc, (double)ls);
    }
}

extern "C" void kernel_launch(void* const* d_in, const int* in_sizes, int n_in,
                              void* d_out, int out_size, void* d_ws, size_t ws_size,
                              hipStream_t stream) {
    const float* X       = (const float*)d_in[0];   // [N, D]
    const float* C       = (const float*)d_in[1];   // [K, D]
    const int*   counts0 = (const int*)d_in[2];     // [K]
    float* out = (float*)d_out;

    // workspace layout
    char* p = (char*)d_ws;
    float*  seg     = (float*)p;          p += (size_t)K * D * 4;   // 4 MB (fallback / sort scratch)
    int*    cnt     = (int*)p;            p += (size_t)K * 4;       // 16 KB
    float*  c2      = (float*)p;          p += (size_t)K * 4;       // 16 KB
    double* lossAcc = (double*)p;         p += 16;
    size_t zero_all = (size_t)(p - (char*)d_ws);
    float*  cand    = (float*)p;          p += (size_t)N * 32 * 4;  // 8 MB (16 cands/row)
    unsigned short* Xh = (unsigned short*)p; p += (size_t)N * D * 2; // 32 MB
    unsigned short* Ch = (unsigned short*)p; p += (size_t)K * D * 2; //  2 MB
    float* xsq_part = (float*)p;          p += 8192 * 4;            // 32 KB
    float* lossC    = (float*)p;          p += (size_t)K * 4;       // 16 KB
    size_t need = (size_t)(p - (char*)d_ws);                        // ~46 MB

    // sort scratch reuses the seg region (mfma path never touches seg)
    int* labInt    = (int*)seg;                  // N ints
    int* sortedIdx = labInt + N;                 // N ints
    int* offs      = sortedIdx + N;              // K ints
    int* cursor    = offs + K;                   // K ints

    if (ws_size >= need) {
        hipMemsetAsync(cnt, 0, (size_t)K * 4, stream);  // histogram only
        convert_f16_both<<<(N*D/8 + K*D/8)/256, 256, 0, stream>>>(X, C, Xh, Ch, xsq_part, c2);
        mfma_assign<<<dim3(N/128, 4), 256, 0, stream>>>(Xh, Ch, c2, cand);
        recheck_label<<<N/16, 256, 0, stream>>>(X, C, c2, cand, out, labInt, cnt);
        prefix_kernel<<<1, 64, 0, stream>>>(cnt, offs, cursor);
        scatter_idx<<<N/256, 256, 0, stream>>>(labInt, cursor, sortedIdx);
        center_update<<<K, 256, 0, stream>>>(X, C, counts0, cnt, offs, sortedIdx, lossC, out);
        loss_final<<<1, 256, 0, stream>>>(xsq_part, lossC, out);
    } else {
        hipMemsetAsync(d_ws, 0, zero_all, stream);
        prep_c2<<<K, 64, 0, stream>>>(C, c2);
        assign_fp32<<<N/128, 256, 0, stream>>>(X, C, c2, out, seg, cnt, lossAcc);
        finalize_kernel<<<(K*D)/256, 256, 0, stream>>>(C, counts0, seg, cnt, lossAcc, out);
    }
}